// Round 7
// baseline (184.230 us; speedup 1.0000x reference)
//
#include <hip/hip_runtime.h>
#include <hip/hip_bf16.h>
#include <math.h>

#define DD 1024
#define MM 8192

typedef __attribute__((ext_vector_type(8))) short short8;
typedef __attribute__((ext_vector_type(4))) float f32x4;

__device__ inline unsigned short f32_to_bf16(float f) {
  union { float f; unsigned u; } v; v.f = f;
  unsigned u = v.u;
  u += 0x7FFFu + ((u >> 16) & 1u);   // round-to-nearest-even
  return (unsigned short)(u >> 16);
}

// Fused prep: [0,4096) x->bf16 convert; [4096,8192) W transpose f32->bf16^T;
// [8192] vqc scale vector.
__global__ void k_prep(const float* __restrict__ x, unsigned short* __restrict__ xb,
                       const float* __restrict__ w0, const float* __restrict__ w1,
                       const float* __restrict__ w2, const float* __restrict__ w3,
                       unsigned short* __restrict__ o0, unsigned short* __restrict__ o1,
                       unsigned short* __restrict__ o2, unsigned short* __restrict__ o3,
                       const float* __restrict__ vqc, float* __restrict__ sc) {
  const int bid = blockIdx.x, tid = threadIdx.x;
  if (bid < 4096) {
    const float4* xv = (const float4*)x;
    ushort4* ov = (ushort4*)xb;
    int i = bid * 256 + tid;
    #pragma unroll
    for (int r = 0; r < 2; r++, i += 4096 * 256) {
      float4 v = xv[i];
      ushort4 u;
      u.x = f32_to_bf16(v.x); u.y = f32_to_bf16(v.y);
      u.z = f32_to_bf16(v.z); u.w = f32_to_bf16(v.w);
      ov[i] = u;
    }
  } else if (bid < 8192) {
    const int rel = bid - 4096;
    const float* src; unsigned short* dst;
    switch (rel >> 10) {
      case 0: src = w0; dst = o0; break;
      case 1: src = w1; dst = o1; break;
      case 2: src = w2; dst = o2; break;
      default: src = w3; dst = o3; break;
    }
    const int t = rel & 1023;
    const int r0 = (t >> 5) * 32, c0 = (t & 31) * 32;
    __shared__ float tl[32][33];
    const int tx = tid & 31, ty = tid >> 5;   // 32 x 8
    #pragma unroll
    for (int i = 0; i < 4; i++)
      tl[ty + 8 * i][tx] = src[(size_t)(r0 + ty + 8 * i) * DD + c0 + tx];
    __syncthreads();
    #pragma unroll
    for (int i = 0; i < 4; i++)
      dst[(size_t)(c0 + ty + 8 * i) * DD + r0 + tx] = f32_to_bf16(tl[tx][ty + 8 * i]);
  } else {
    #pragma unroll
    for (int k = 0; k < 4; k++) {
      int d = tid + k * 256;
      float th = vqc[d * 4 + 0] * 0.5f, ph = vqc[d * 4 + 1];
      sc[d] = cosf(th) + sinf(th) * cosf(ph);
    }
  }
}

// C[M,N] = act(A[M,K] @ B + bias); B given as B^T (N,K) row-major bf16.
// Tile 128x128, BK=64, 4 waves (2Mx2N, 64x64/wave, acc[4][4]).
// KEY CHANGE vs R4: B is NOT staged through LDS. B is 2 MB = L2-resident
// (per-XCD slice fits 4 MB L2); B-fragments load straight from global into
// registers (per-lane dwordx4, 64B-coalesced per row, reused over 4 MFMAs).
// This cuts per-CU LDS traffic ~3x -> below the matrix-pipe demand
// (the measured bottleneck of R2/R4; catalog Common-mistake #7).
// A keeps LDS staging (reused by both wc-waves) with the both-sides XOR
// swizzle (slot ^= row&7). 2-barrier structure (proven). 16 KB LDS.
// Grid 512 = 2 blocks/CU. XCD map: bx = L>>6, by = L&63 -> all 8 column
// blocks of an A-panel share L%8 -> one XCD's L2.
// EPI: 0=tanh->bf16, 1=(z+b)*scale[n]->bf16, 2=silu->bf16, 3=identity->f32
template <int EPI>
__launch_bounds__(256, 2)
__global__ void k_gemm(const unsigned short* __restrict__ A,
                       const unsigned short* __restrict__ Bt,
                       const float* __restrict__ bias,
                       const float* __restrict__ scale,
                       void* __restrict__ Cout) {
  constexpr int K = DD, N = DD;
  __shared__ unsigned short As[128 * 64];   // 16 KB
  const int tid = threadIdx.x;
  const int wave = tid >> 6, lane = tid & 63;
  const int wr = wave >> 1, wc = wave & 1;  // 2M x 2N waves, 64x64 each

  const int L = blockIdx.x;                 // 1D grid, 512 blocks
  const int bx = L >> 6, by = L & 63;
  const int rowA0 = by * 128, colB0 = bx * 128;

  const int lr = lane & 15, lks = lane >> 4;  // frag row-in-frag, k-slot
  const int srow = lane >> 3;                 // staging row within 8-row seg
  const int sswz = ((lane & 7) ^ srow) * 8;   // pre-swizzled k-slot (shorts)

  // A staging row bases (global, pre-swizzled k)
  const unsigned short* gA[4];
  #pragma unroll
  for (int i = 0; i < 4; i++)
    gA[i] = A + (size_t)(rowA0 + i * 32 + wave * 8 + srow) * K + sswz;

  // B fragment pointers: row = colB0 + wc*64 + n*16 + lr, k-offset lks*8
  const unsigned short* gBf[4];
  #pragma unroll
  for (int n = 0; n < 4; n++)
    gBf[n] = Bt + (size_t)(colB0 + wc * 64 + n * 16 + lr) * K + lks * 8;

  f32x4 acc[4][4] = {};

  for (int k0 = 0; k0 < K; k0 += 64) {
    // B fragments straight from global (L1/L2) into registers.
    short8 bfr[2][4];
    #pragma unroll
    for (int kk2 = 0; kk2 < 2; kk2++)
      #pragma unroll
      for (int n = 0; n < 4; n++)
        bfr[kk2][n] = *(const short8*)(gBf[n] + k0 + kk2 * 32);

    // A tile -> LDS (async, linear dest, pre-swizzled source)
    #pragma unroll
    for (int i = 0; i < 4; i++)
      __builtin_amdgcn_global_load_lds(
          (const __attribute__((address_space(1))) unsigned int*)(gA[i] + k0),
          (__attribute__((address_space(3))) unsigned int*)(As + (i * 32 + wave * 8) * 64),
          16, 0, 0);

    __syncthreads();   // drains vmcnt: A tile in LDS, B frags in regs

    #pragma unroll
    for (int kk2 = 0; kk2 < 2; kk2++) {
      short8 a[4];
      #pragma unroll
      for (int m = 0; m < 4; m++) {
        int row = wr * 64 + m * 16 + lr;
        a[m] = *(const short8*)(As + row * 64 + ((((kk2 * 4) + lks) ^ (row & 7)) << 3));
      }
      #pragma unroll
      for (int m = 0; m < 4; m++)
        #pragma unroll
        for (int n = 0; n < 4; n++)
          acc[m][n] = __builtin_amdgcn_mfma_f32_16x16x32_bf16(a[m], bfr[kk2][n], acc[m][n], 0, 0, 0);
    }
    __syncthreads();   // all waves done reading As before next overwrite
  }

  // Epilogue. C/D layout: col = lane&15, row = (lane>>4)*4 + j  [m89/m91]
  const int row0 = rowA0 + wr * 64;
  const int col0 = colB0 + wc * 64;
  #pragma unroll
  for (int n = 0; n < 4; n++) {
    const int col = col0 + n * 16 + lr;
    const float bv = bias[col];
    const float sv = (EPI == 1) ? scale[col] : 0.f;
    #pragma unroll
    for (int m = 0; m < 4; m++) {
      #pragma unroll
      for (int j = 0; j < 4; j++) {
        int row = row0 + m * 16 + lks * 4 + j;
        float z = acc[m][n][j] + bv;
        if constexpr (EPI == 0) {
          ((unsigned short*)Cout)[(size_t)row * N + col] = f32_to_bf16(tanhf(z));
        } else if constexpr (EPI == 1) {
          ((unsigned short*)Cout)[(size_t)row * N + col] = f32_to_bf16(z * sv);
        } else if constexpr (EPI == 2) {
          ((unsigned short*)Cout)[(size_t)row * N + col] = f32_to_bf16(z / (1.f + __expf(-z)));
        } else {
          ((float*)Cout)[(size_t)row * N + col] = z;
        }
      }
    }
  }
}

extern "C" void kernel_launch(void* const* d_in, const int* in_sizes, int n_in,
                              void* d_out, int out_size, void* d_ws, size_t ws_size,
                              hipStream_t stream) {
  const float* x   = (const float*)d_in[0];
  const float* W1  = (const float*)d_in[1];
  const float* b1  = (const float*)d_in[2];
  const float* W2  = (const float*)d_in[3];
  const float* b2  = (const float*)d_in[4];
  const float* vqc = (const float*)d_in[5];
  const float* Wp1 = (const float*)d_in[6];
  const float* bp1 = (const float*)d_in[7];
  const float* Wp2 = (const float*)d_in[8];
  const float* bp2 = (const float*)d_in[9];

  char* ws = (char*)d_ws;
  unsigned short* actA = (unsigned short*)ws;                    // 16 MB: xb, then gemm2 out
  unsigned short* actB = (unsigned short*)(ws + (16u << 20));    // 16 MB: gemm1/gemm3 out
  unsigned short* Wt0  = (unsigned short*)(ws + (32u << 20));    // 2 MB each
  unsigned short* Wt1  = (unsigned short*)(ws + (34u << 20));
  unsigned short* Wt2  = (unsigned short*)(ws + (36u << 20));
  unsigned short* Wt3  = (unsigned short*)(ws + (38u << 20));
  float* scale = (float*)(ws + (40u << 20));                     // 4 KB

  k_prep<<<8193, 256, 0, stream>>>(x, actA, W1, W2, Wp1, Wp2,
                                   Wt0, Wt1, Wt2, Wt3, vqc, scale);

  dim3 g(512), b(256);
  k_gemm<0><<<g, b, 0, stream>>>(actA, Wt0, b1,  nullptr, actB);   // tanh(x@W1+b1)
  k_gemm<1><<<g, b, 0, stream>>>(actB, Wt1, b2,  scale,   actA);   // (·@W2+b2)*scale
  k_gemm<2><<<g, b, 0, stream>>>(actA, Wt2, bp1, nullptr, actB);   // silu(q@Wp1+bp1)
  k_gemm<3><<<g, b, 0, stream>>>(actB, Wt3, bp2, nullptr, d_out);  // ·@Wp2+bp2 -> f32
}

// Round 10
// 135.001 us; speedup vs baseline: 1.3647x; 1.3647x over previous
//
#include <hip/hip_runtime.h>
#include <hip/hip_bf16.h>
#include <math.h>

#define DD 1024
#define MM 8192

typedef __attribute__((ext_vector_type(8))) short short8;
typedef __attribute__((ext_vector_type(4))) float f32x4;

__device__ inline unsigned short f32_to_bf16(float f) {
  union { float f; unsigned u; } v; v.f = f;
  unsigned u = v.u;
  u += 0x7FFFu + ((u >> 16) & 1u);   // round-to-nearest-even
  return (unsigned short)(u >> 16);
}

// Fused prep: [0,4096) x->bf16 convert; [4096,8192) W transpose f32->bf16^T;
// [8192] vqc scale vector.
__global__ void k_prep(const float* __restrict__ x, unsigned short* __restrict__ xb,
                       const float* __restrict__ w0, const float* __restrict__ w1,
                       const float* __restrict__ w2, const float* __restrict__ w3,
                       unsigned short* __restrict__ o0, unsigned short* __restrict__ o1,
                       unsigned short* __restrict__ o2, unsigned short* __restrict__ o3,
                       const float* __restrict__ vqc, float* __restrict__ sc) {
  const int bid = blockIdx.x, tid = threadIdx.x;
  if (bid < 4096) {
    const float4* xv = (const float4*)x;
    ushort4* ov = (ushort4*)xb;
    int i = bid * 256 + tid;
    #pragma unroll
    for (int r = 0; r < 2; r++, i += 4096 * 256) {
      float4 v = xv[i];
      ushort4 u;
      u.x = f32_to_bf16(v.x); u.y = f32_to_bf16(v.y);
      u.z = f32_to_bf16(v.z); u.w = f32_to_bf16(v.w);
      ov[i] = u;
    }
  } else if (bid < 8192) {
    const int rel = bid - 4096;
    const float* src; unsigned short* dst;
    switch (rel >> 10) {
      case 0: src = w0; dst = o0; break;
      case 1: src = w1; dst = o1; break;
      case 2: src = w2; dst = o2; break;
      default: src = w3; dst = o3; break;
    }
    const int t = rel & 1023;
    const int r0 = (t >> 5) * 32, c0 = (t & 31) * 32;
    __shared__ float tl[32][33];
    const int tx = tid & 31, ty = tid >> 5;   // 32 x 8
    #pragma unroll
    for (int i = 0; i < 4; i++)
      tl[ty + 8 * i][tx] = src[(size_t)(r0 + ty + 8 * i) * DD + c0 + tx];
    __syncthreads();
    #pragma unroll
    for (int i = 0; i < 4; i++)
      dst[(size_t)(c0 + ty + 8 * i) * DD + r0 + tx] = f32_to_bf16(tl[tx][ty + 8 * i]);
  } else {
    #pragma unroll
    for (int k = 0; k < 4; k++) {
      int d = tid + k * 256;
      float th = vqc[d * 4 + 0] * 0.5f, ph = vqc[d * 4 + 1];
      sc[d] = cosf(th) + sinf(th) * cosf(ph);
    }
  }
}

// Faithful m201-style 8-phase schedule, adapted to BM=256 BN=128 BK=64.
// 8 waves (2M x 4N, 128x32/wave, acc[8][2]). Double-buffered LDS (96 KB,
// 1 block/CU, 2 waves/SIMD). Iter = 2 K-tiles = 8 phases; each phase =
// {6 ds_read_b128; 2 global_load_lds; s_barrier; setprio1; 8 MFMA;
//  setprio0; [counted vmcnt]; s_barrier}.
// Stage plan per iter (tiles T=2i in buf0, T+1 in buf1):
//   ph0: A-half0(T+1)  ph1: B(T+1)  ph2: A-half1(T+1)  ph3: -
//   ph4: A-half0(T+2)  ph5: B(T+2)  ph6: A-half1(T+2)  ph7: -
// Load-ledger waits (before the phase-end barrier; vmcnt+barrier = all-waves):
//   end-ph1: vmcnt(4)  [A1(T) landed; newest 4 = A0(T+1),B(T+1)]
//   end-ph3: vmcnt(2)  [A0,B(T+1) landed; newest 2 = A1(T+1)]
//   end-ph5: vmcnt(4)  end-ph7: vmcnt(2)
// Never vmcnt(0) mid-loop; last iter drains once at end-ph5.
// T2 XOR swizzle both-sides (slot ^= row&7). XCD map: by=L&31 ->
// same-A-panel blocks share L%8 -> one XCD; per-XCD set = 4MB = L2.
// EPI: 0=tanh->bf16, 1=(z+b)*scale[n]->bf16, 2=silu->bf16, 3=identity->f32
#define BARR    asm volatile("s_barrier" ::: "memory")
#define VM4BARR asm volatile("s_waitcnt vmcnt(4)\ns_barrier" ::: "memory")
#define VM2BARR asm volatile("s_waitcnt vmcnt(2)\ns_barrier" ::: "memory")
#define VM0BARR asm volatile("s_waitcnt vmcnt(0)\ns_barrier" ::: "memory")
#define NOOP    ((void)0)

#define PH(BUF, H, KK, STAGE_STMT, TAIL_STMT)                                  \
  {                                                                            \
    short8 a_[4], b_[2];                                                       \
    _Pragma("unroll")                                                          \
    for (int m2 = 0; m2 < 4; m2++) {                                           \
      const int row = wr * 128 + (H) * 64 + m2 * 16 + lr;                      \
      a_[m2] = *(const short8*)(&As[BUF][row * 64 +                            \
                  ((((KK) * 4 + lks) ^ (row & 7)) << 3)]);                     \
    }                                                                          \
    _Pragma("unroll")                                                          \
    for (int n = 0; n < 2; n++) {                                              \
      const int row = wc * 32 + n * 16 + lr;                                   \
      b_[n] = *(const short8*)(&Bs[BUF][row * 64 +                             \
                  ((((KK) * 4 + lks) ^ (row & 7)) << 3)]);                     \
    }                                                                          \
    STAGE_STMT;                                                                \
    asm volatile("s_barrier" ::: "memory");                                    \
    __builtin_amdgcn_s_setprio(1);                                             \
    _Pragma("unroll")                                                          \
    for (int m2 = 0; m2 < 4; m2++)                                             \
      _Pragma("unroll")                                                        \
      for (int n = 0; n < 2; n++)                                              \
        acc[(H) * 4 + m2][n] = __builtin_amdgcn_mfma_f32_16x16x32_bf16(        \
            a_[m2], b_[n], acc[(H) * 4 + m2][n], 0, 0, 0);                     \
    __builtin_amdgcn_s_setprio(0);                                             \
    TAIL_STMT;                                                                 \
  }

template <int EPI>
__launch_bounds__(512, 2)
__global__ void k_gemm(const unsigned short* __restrict__ A,
                       const unsigned short* __restrict__ Bt,
                       const float* __restrict__ bias,
                       const float* __restrict__ scale,
                       void* __restrict__ Cout) {
  constexpr int K = DD, N = DD;
  __shared__ unsigned short As[2][256 * 64];   // 64 KB
  __shared__ unsigned short Bs[2][128 * 64];   // 32 KB
  const int tid = threadIdx.x;
  const int wave = tid >> 6, lane = tid & 63;
  const int wr = wave >> 2, wc = wave & 3;     // 2M x 4N waves

  const int L = blockIdx.x;                    // grid 256 = 32 by x 8 bx
  const int by = L & 31, bx = L >> 5;          // same-by blocks: L%8 const
  const int rowA0 = by * 256, colB0 = bx * 128;

  const int lr = lane & 15, lks = lane >> 4;
  const int srow = lane >> 3;
  const int sswz = ((lane & 7) ^ srow) * 8;    // pre-swizzled k-slot (shorts)

  const unsigned short* gAp[2][2];   // [half][round]
  #pragma unroll
  for (int h = 0; h < 2; h++)
    #pragma unroll
    for (int r = 0; r < 2; r++)
      gAp[h][r] = A + (size_t)(rowA0 + h * 128 + r * 64 + wave * 8 + srow) * K + sswz;
  const unsigned short* gBp[2];
  #pragma unroll
  for (int r = 0; r < 2; r++)
    gBp[r] = Bt + (size_t)(colB0 + r * 64 + wave * 8 + srow) * K + sswz;

  auto stageA = [&](int buf, int t, int h) {
    #pragma unroll
    for (int r = 0; r < 2; r++)
      __builtin_amdgcn_global_load_lds(
          (const __attribute__((address_space(1))) unsigned int*)(gAp[h][r] + t * 64),
          (__attribute__((address_space(3))) unsigned int*)(&As[buf][(h * 128 + r * 64 + wave * 8) * 64]),
          16, 0, 0);
  };
  auto stageB = [&](int buf, int t) {
    #pragma unroll
    for (int r = 0; r < 2; r++)
      __builtin_amdgcn_global_load_lds(
          (const __attribute__((address_space(1))) unsigned int*)(gBp[r] + t * 64),
          (__attribute__((address_space(3))) unsigned int*)(&Bs[buf][(r * 64 + wave * 8) * 64]),
          16, 0, 0);
  };

  f32x4 acc[8][2] = {};

  // Prologue: tile 0 -> buf0 in steady-state order (A0, B, A1).
  stageA(0, 0, 0);
  stageB(0, 0);
  stageA(0, 0, 1);
  asm volatile("s_waitcnt vmcnt(2)\ns_barrier" ::: "memory");  // A0,B landed

  #pragma unroll 1
  for (int i = 0; i < 8; ++i) {
    const int tt = 2 * i;
    PH(0, 0, 0, stageA(1, tt + 1, 0), BARR);
    PH(0, 0, 1, stageB(1, tt + 1),    VM4BARR);
    PH(0, 1, 0, stageA(1, tt + 1, 1), BARR);
    PH(0, 1, 1, NOOP,                 VM2BARR);
    if (i < 7) {
      PH(1, 0, 0, stageA(0, tt + 2, 0), BARR);
      PH(1, 0, 1, stageB(0, tt + 2),    VM4BARR);
      PH(1, 1, 0, stageA(0, tt + 2, 1), BARR);
      PH(1, 1, 1, NOOP,                 VM2BARR);
    } else {
      PH(1, 0, 0, NOOP, BARR);
      PH(1, 0, 1, NOOP, VM0BARR);   // drain once: A1(15) needed next
      PH(1, 1, 0, NOOP, BARR);
      PH(1, 1, 1, NOOP, NOOP);      // last phase: straight to epilogue
    }
  }

  // Epilogue. C/D layout: col = lane&15, row = (lane>>4)*4 + j  [m89/m91]
  const int row0 = rowA0 + wr * 128;
  const int col0 = colB0 + wc * 32;
  #pragma unroll
  for (int n = 0; n < 2; n++) {
    const int col = col0 + n * 16 + lr;
    const float bv = bias[col];
    const float sv = (EPI == 1) ? scale[col] : 0.f;
    #pragma unroll
    for (int f = 0; f < 8; f++) {
      const int moff = (f >> 2) * 64 + (f & 3) * 16;
      #pragma unroll
      for (int j = 0; j < 4; j++) {
        int row = row0 + moff + lks * 4 + j;
        float z = acc[f][n][j] + bv;
        if constexpr (EPI == 0) {
          ((unsigned short*)Cout)[(size_t)row * N + col] = f32_to_bf16(tanhf(z));
        } else if constexpr (EPI == 1) {
          ((unsigned short*)Cout)[(size_t)row * N + col] = f32_to_bf16(z * sv);
        } else if constexpr (EPI == 2) {
          ((unsigned short*)Cout)[(size_t)row * N + col] = f32_to_bf16(z / (1.f + __expf(-z)));
        } else {
          ((float*)Cout)[(size_t)row * N + col] = z;
        }
      }
    }
  }
}

extern "C" void kernel_launch(void* const* d_in, const int* in_sizes, int n_in,
                              void* d_out, int out_size, void* d_ws, size_t ws_size,
                              hipStream_t stream) {
  const float* x   = (const float*)d_in[0];
  const float* W1  = (const float*)d_in[1];
  const float* b1  = (const float*)d_in[2];
  const float* W2  = (const float*)d_in[3];
  const float* b2  = (const float*)d_in[4];
  const float* vqc = (const float*)d_in[5];
  const float* Wp1 = (const float*)d_in[6];
  const float* bp1 = (const float*)d_in[7];
  const float* Wp2 = (const float*)d_in[8];
  const float* bp2 = (const float*)d_in[9];

  char* ws = (char*)d_ws;
  unsigned short* actA = (unsigned short*)ws;                    // 16 MB: xb, then gemm2 out
  unsigned short* actB = (unsigned short*)(ws + (16u << 20));    // 16 MB: gemm1/gemm3 out
  unsigned short* Wt0  = (unsigned short*)(ws + (32u << 20));    // 2 MB each
  unsigned short* Wt1  = (unsigned short*)(ws + (34u << 20));
  unsigned short* Wt2  = (unsigned short*)(ws + (36u << 20));
  unsigned short* Wt3  = (unsigned short*)(ws + (38u << 20));
  float* scale = (float*)(ws + (40u << 20));                     // 4 KB

  k_prep<<<8193, 256, 0, stream>>>(x, actA, W1, W2, Wp1, Wp2,
                                   Wt0, Wt1, Wt2, Wt3, vqc, scale);

  dim3 g(256), b(512);
  k_gemm<0><<<g, b, 0, stream>>>(actA, Wt0, b1,  nullptr, actB);   // tanh(x@W1+b1)
  k_gemm<1><<<g, b, 0, stream>>>(actB, Wt1, b2,  scale,   actA);   // (·@W2+b2)*scale
  k_gemm<2><<<g, b, 0, stream>>>(actA, Wt2, bp1, nullptr, actB);   // silu(q@Wp1+bp1)
  k_gemm<3><<<g, b, 0, stream>>>(actB, Wt3, bp2, nullptr, d_out);  // ·@Wp2+bp2 -> f32
}